// Round 8
// baseline (392.526 us; speedup 1.0000x reference)
//
#include <hip/hip_runtime.h>

constexpr int NN = 50000;
constexpr int NREL = 3;
constexpr int NE = 400000;
constexpr int MAXSPILL = 4096;

constexpr int G1X = (NN + 63) / 64;           // 782 row-tiles
constexpr int GEMM1_BLKS = G1X * 2 * NREL;    // 4692 blocks; >= 4688 edge chunks
constexpr int LDA = 68;                       // BK=64 + 4 pad
constexpr int CAP8 = 10;                      // per-XCD ELL cap (Poisson(1) tail ~1e-7)
constexpr int CAP1 = 24;                      // single-replica fallback cap
constexpr size_t CS = (size_t)2 * NREL * NN;  // counter stride per replica ([out|in])

// ---- bf16 <-> f32 bit helpers (finite inputs; RNE on store) ----
__device__ __forceinline__ float b2f(unsigned short u) {
  union { unsigned int i; float f; } v; v.i = (unsigned int)u << 16; return v.f;
}
__device__ __forceinline__ unsigned short f2b(float f) {
  union { float f; unsigned int i; } v; v.f = f;
  unsigned int r = v.i + 0x7fffu + ((v.i >> 16) & 1u);
  return (unsigned short)(r >> 16);
}

// ---- GEMM tile body, BK=64 two-stage: C_bf16[M][N] = (A * rsqrt(cnt)?) @ W_f32 ----
template <bool SCALE, bool INBF>
__device__ __forceinline__ void gemm_body(
    const void* __restrict__ Av, const float* __restrict__ W,
    const int* __restrict__ cnt_scale, unsigned short* __restrict__ C,
    int M, int N, int row0, int col0) {
  __shared__ float As[64][LDA];
  __shared__ float Bs[64][64];
  int t = threadIdx.x;
  int tx4 = (t & 15) << 2;
  int ty4 = (t >> 4) << 2;
  float acc[4][4] = {};
  for (int k0 = 0; k0 < 128; k0 += 64) {
    if (k0) __syncthreads();
#pragma unroll
    for (int i = 0; i < 4; ++i) {
      int idx = t + i * 256;
      int r = idx >> 4;
      int c4 = (idx & 15) << 2;
      int grow = row0 + r;
      float4 v = make_float4(0.f, 0.f, 0.f, 0.f);
      if (grow < M) {
        if (INBF) {
          ushort4 u = *(const ushort4*)((const unsigned short*)Av + (size_t)grow * 128 + k0 + c4);
          v = make_float4(b2f(u.x), b2f(u.y), b2f(u.z), b2f(u.w));
        } else {
          v = *(const float4*)((const float*)Av + (size_t)grow * 128 + k0 + c4);
        }
        if (SCALE) {
          float s = rsqrtf((float)max(cnt_scale[grow], 1));
          v.x *= s; v.y *= s; v.z *= s; v.w *= s;
        }
      }
      *(float4*)(&As[r][c4]) = v;
    }
#pragma unroll
    for (int i = 0; i < 4; ++i) {
      int idx = t + i * 256;
      int k = idx >> 4;
      int c4 = (idx & 15) << 2;
      *(float4*)(&Bs[k][c4]) = *(const float4*)(W + (size_t)(k0 + k) * N + col0 + c4);
    }
    __syncthreads();
#pragma unroll 8
    for (int k = 0; k < 64; k += 4) {
      float4 b0 = *(const float4*)(&Bs[k + 0][tx4]);
      float4 b1 = *(const float4*)(&Bs[k + 1][tx4]);
      float4 b2 = *(const float4*)(&Bs[k + 2][tx4]);
      float4 b3 = *(const float4*)(&Bs[k + 3][tx4]);
#pragma unroll
      for (int m = 0; m < 4; ++m) {
        float4 a = *(const float4*)(&As[ty4 + m][k]);
        acc[m][0] += a.x * b0.x + a.y * b1.x + a.z * b2.x + a.w * b3.x;
        acc[m][1] += a.x * b0.y + a.y * b1.y + a.z * b2.y + a.w * b3.y;
        acc[m][2] += a.x * b0.z + a.y * b1.z + a.z * b2.z + a.w * b3.z;
        acc[m][3] += a.x * b0.w + a.y * b1.w + a.z * b2.w + a.w * b3.w;
      }
    }
  }
#pragma unroll
  for (int m = 0; m < 4; ++m) {
    int row = row0 + ty4 + m;
    if (row < M) {
      ushort4 o;
      o.x = f2b(acc[m][0]); o.y = f2b(acc[m][1]);
      o.z = f2b(acc[m][2]); o.w = f2b(acc[m][3]);
      *(ushort4*)(C + (size_t)row * N + col0 + tx4) = o;
    }
  }
}

// ---- fused: 1 GEMM tile of proj1_r = x@W1_r + 256 edges of XCD-replicated ELL build ----
// R replicas; WG=true -> workgroup-scope atomics on own-XCD replica (L2-local RMW).
// Correct regardless of whether the compiler honors the scope (replicas + reduce).
template <int R, int CAPR, bool WG>
__global__ __launch_bounds__(256, 3) void fused_build_gemm1_kernel(
    const int* __restrict__ edges, int* __restrict__ cnt8,
    unsigned short* __restrict__ ell8, int* __restrict__ nspill, int* __restrict__ spill,
    const float* __restrict__ x, const float* __restrict__ W1, unsigned short* __restrict__ proj1) {
  __shared__ float As[64][LDA];
  __shared__ float Bs[64][64];
  int t = threadIdx.x;

  int rep = 0;
  if (R > 1) {
    unsigned int xcc;
    asm volatile("s_getreg_b32 %0, hwreg(HW_REG_XCC_ID)" : "=s"(xcc));
    rep = (int)(xcc & (unsigned)(R - 1));
  }

  // --- edge slice ---
  int eg = blockIdx.x * 256 + t;
  bool have = (eg < NREL * NE);
  int er = 0, es = 0, ed = 0;
  if (have) {
    er = eg / NE;
    int e = eg - er * NE;
    const int* b = edges + (size_t)er * 2 * NE;
    es = b[e];
    ed = b[NE + e];
  }

  // --- GEMM tile mapping ---
  int g = blockIdx.x;
  int r = g / (G1X * 2);
  int rem = g - r * (G1X * 2);
  int row0 = (rem >> 1) * 64;
  int col0 = (rem & 1) * 64;
  const float* W = W1 + (size_t)r * 128 * 128;
  unsigned short* C = proj1 + (size_t)r * NN * 128;

  int tx4 = (t & 15) << 2;
  int ty4 = (t >> 4) << 2;
  float acc[4][4] = {};
  int pos = 0;
  for (int k0 = 0; k0 < 128; k0 += 64) {
    if (k0) __syncthreads();
#pragma unroll
    for (int i = 0; i < 4; ++i) {
      int idx = t + i * 256;
      int rr = idx >> 4;
      int c4 = (idx & 15) << 2;
      int grow = row0 + rr;
      float4 v = make_float4(0.f, 0.f, 0.f, 0.f);
      if (grow < NN) v = *(const float4*)(x + (size_t)grow * 128 + k0 + c4);
      *(float4*)(&As[rr][c4]) = v;
    }
#pragma unroll
    for (int i = 0; i < 4; ++i) {
      int idx = t + i * 256;
      int k = idx >> 4;
      int c4 = (idx & 15) << 2;
      *(float4*)(&Bs[k][c4]) = *(const float4*)(W + (size_t)(k0 + k) * 128 + col0 + c4);
    }
    __syncthreads();
    if (k0 == 0 && have) {
      int* pout = cnt8 + rep * CS + (size_t)er * NN + es;
      int* pin  = cnt8 + rep * CS + (size_t)NREL * NN + (size_t)er * NN + ed;
      if (WG) {
        __hip_atomic_fetch_add(pout, 1, __ATOMIC_RELAXED, __HIP_MEMORY_SCOPE_WORKGROUP);
        pos = __hip_atomic_fetch_add(pin, 1, __ATOMIC_RELAXED, __HIP_MEMORY_SCOPE_WORKGROUP);
      } else {
        atomicAdd(pout, 1);
        pos = atomicAdd(pin, 1);
      }
    }
#pragma unroll 8
    for (int k = 0; k < 64; k += 4) {
      float4 b0 = *(const float4*)(&Bs[k + 0][tx4]);
      float4 b1 = *(const float4*)(&Bs[k + 1][tx4]);
      float4 b2 = *(const float4*)(&Bs[k + 2][tx4]);
      float4 b3 = *(const float4*)(&Bs[k + 3][tx4]);
#pragma unroll
      for (int m = 0; m < 4; ++m) {
        float4 a = *(const float4*)(&As[ty4 + m][k]);
        acc[m][0] += a.x * b0.x + a.y * b1.x + a.z * b2.x + a.w * b3.x;
        acc[m][1] += a.x * b0.y + a.y * b1.y + a.z * b2.y + a.w * b3.y;
        acc[m][2] += a.x * b0.z + a.y * b1.z + a.z * b2.z + a.w * b3.z;
        acc[m][3] += a.x * b0.w + a.y * b1.w + a.z * b2.w + a.w * b3.w;
      }
    }
  }
#pragma unroll
  for (int m = 0; m < 4; ++m) {
    int row = row0 + ty4 + m;
    if (row < NN) {
      ushort4 o;
      o.x = f2b(acc[m][0]); o.y = f2b(acc[m][1]);
      o.z = f2b(acc[m][2]); o.w = f2b(acc[m][3]);
      *(ushort4*)(C + (size_t)row * 128 + col0 + tx4) = o;
    }
  }

  if (have) {
    if (pos < CAPR) {
      ell8[(((size_t)rep * NREL + er) * NN + ed) * CAPR + pos] = (unsigned short)es;
    } else {
      int i = atomicAdd(nspill, 1);  // rare; device scope
      if (i < MAXSPILL) { spill[3 * i] = er; spill[3 * i + 1] = ed; spill[3 * i + 2] = es; }
    }
  }
}

// sum replicas -> canonical counts ([out|in], length CS)
__global__ void reduce_counts_kernel(const int* __restrict__ cnt8, int* __restrict__ cnt, int reps) {
  int i = blockIdx.x * blockDim.x + threadIdx.x;
  if (i >= (int)CS) return;
  int s = 0;
  for (int rr = 0; rr < reps; ++rr) s += cnt8[rr * CS + i];
  cnt[i] = s;
}

__global__ __launch_bounds__(256, 3) void gemm2_kernel(
    const unsigned short* __restrict__ h, const float* __restrict__ W2,
    const int* __restrict__ cnt, unsigned short* __restrict__ proj2) {
  int r = blockIdx.z;
  gemm_body<true, true>(h, W2 + (size_t)r * 128 * 64, cnt + (size_t)r * NN,
                        proj2 + (size_t)r * NN * 64, NN, 64, blockIdx.x * 64, 0);
}

// ---- layer-1 aggregate over all relations and replicas; bias+relu fused; half-wave/row ----
__global__ __launch_bounds__(256) void agg1_all_kernel(
    const unsigned short* __restrict__ proj1, const unsigned short* __restrict__ ell8,
    const int* __restrict__ cnt8, const int* __restrict__ cnt,
    const int* __restrict__ nspill, const int* __restrict__ spill,
    const float* __restrict__ b1, unsigned short* __restrict__ h, int reps, int capr) {
  int row = (blockIdx.x * blockDim.x + threadIdx.x) >> 5;
  if (row >= NN) return;
  int lane = threadIdx.x & 31;
  int f = lane * 4;
  float4 q0 = *(const float4*)(b1 + f);
  float4 q1 = *(const float4*)(b1 + 128 + f);
  float4 q2 = *(const float4*)(b1 + 256 + f);
  float4 acc = make_float4(q0.x + q1.x + q2.x, q0.y + q1.y + q2.y,
                           q0.z + q1.z + q2.z, q0.w + q1.w + q2.w);
  int ns = min(*nspill, MAXSPILL);
  for (int r = 0; r < NREL; ++r) {
    const unsigned short* P = proj1 + (size_t)r * NN * 128;
    const int* co = cnt + (size_t)r * NN;
    int deg = cnt[NREL * NN + (size_t)r * NN + row];
    float4 a0 = make_float4(0.f, 0.f, 0.f, 0.f);
    for (int rep = 0; rep < reps; ++rep) {
      int n = min(cnt8[rep * CS + NREL * NN + (size_t)r * NN + row], capr);
      const unsigned short* er = ell8 + (((size_t)rep * NREL + r) * NN + row) * capr;
      for (int e = 0; e < n; ++e) {
        int s0 = er[e];
        float w0 = rsqrtf((float)max(co[s0], 1));
        ushort4 u0 = *(const ushort4*)(P + (size_t)s0 * 128 + f);
        a0.x += w0 * b2f(u0.x); a0.y += w0 * b2f(u0.y);
        a0.z += w0 * b2f(u0.z); a0.w += w0 * b2f(u0.w);
      }
    }
    for (int i = 0; i < ns; ++i) {
      if (spill[3 * i] == r && spill[3 * i + 1] == row) {
        int s0 = spill[3 * i + 2];
        float w0 = rsqrtf((float)max(co[s0], 1));
        ushort4 u0 = *(const ushort4*)(P + (size_t)s0 * 128 + f);
        a0.x += w0 * b2f(u0.x); a0.y += w0 * b2f(u0.y);
        a0.z += w0 * b2f(u0.z); a0.w += w0 * b2f(u0.w);
      }
    }
    float si = rsqrtf((float)max(deg, 1));
    acc.x += a0.x * si; acc.y += a0.y * si;
    acc.z += a0.z * si; acc.w += a0.w * si;
  }
  ushort4 o;
  o.x = f2b(fmaxf(acc.x, 0.f)); o.y = f2b(fmaxf(acc.y, 0.f));
  o.z = f2b(fmaxf(acc.z, 0.f)); o.w = f2b(fmaxf(acc.w, 0.f));
  *(ushort4*)(h + (size_t)row * 128 + f) = o;
}

// ---- layer-2 aggregate over all relations and replicas; bias fused; quarter-wave/row ----
__global__ __launch_bounds__(256) void agg2_all_kernel(
    const unsigned short* __restrict__ proj2, const unsigned short* __restrict__ ell8,
    const int* __restrict__ cnt8, const int* __restrict__ cnt,
    const int* __restrict__ nspill, const int* __restrict__ spill,
    const float* __restrict__ b2, float* __restrict__ out, int reps, int capr) {
  int row = (blockIdx.x * blockDim.x + threadIdx.x) >> 4;
  if (row >= NN) return;
  int lane = threadIdx.x & 15;
  int f = lane * 4;
  float4 q0 = *(const float4*)(b2 + f);
  float4 q1 = *(const float4*)(b2 + 64 + f);
  float4 q2 = *(const float4*)(b2 + 128 + f);
  float4 acc = make_float4(q0.x + q1.x + q2.x, q0.y + q1.y + q2.y,
                           q0.z + q1.z + q2.z, q0.w + q1.w + q2.w);
  int ns = min(*nspill, MAXSPILL);
  for (int r = 0; r < NREL; ++r) {
    const unsigned short* P = proj2 + (size_t)r * NN * 64;
    int deg = cnt[NREL * NN + (size_t)r * NN + row];
    float4 a0 = make_float4(0.f, 0.f, 0.f, 0.f);
    for (int rep = 0; rep < reps; ++rep) {
      int n = min(cnt8[rep * CS + NREL * NN + (size_t)r * NN + row], capr);
      const unsigned short* er = ell8 + (((size_t)rep * NREL + r) * NN + row) * capr;
      for (int e = 0; e < n; ++e) {
        int s0 = er[e];
        ushort4 u0 = *(const ushort4*)(P + (size_t)s0 * 64 + f);
        a0.x += b2f(u0.x); a0.y += b2f(u0.y); a0.z += b2f(u0.z); a0.w += b2f(u0.w);
      }
    }
    for (int i = 0; i < ns; ++i) {
      if (spill[3 * i] == r && spill[3 * i + 1] == row) {
        int s0 = spill[3 * i + 2];
        ushort4 u0 = *(const ushort4*)(P + (size_t)s0 * 64 + f);
        a0.x += b2f(u0.x); a0.y += b2f(u0.y); a0.z += b2f(u0.z); a0.w += b2f(u0.w);
      }
    }
    float si = rsqrtf((float)max(deg, 1));
    acc.x += a0.x * si; acc.y += a0.y * si;
    acc.z += a0.z * si; acc.w += a0.w * si;
  }
  *(float4*)(out + (size_t)row * 64 + f) = acc;
}

extern "C" void kernel_launch(void* const* d_in, const int* in_sizes, int n_in,
                              void* d_out, int out_size, void* d_ws, size_t ws_size,
                              hipStream_t stream) {
  const float* x   = (const float*)d_in[0];
  const int* edges = (const int*)d_in[1];
  const float* W1  = (const float*)d_in[2];
  const float* b1  = (const float*)d_in[3];
  const float* W2  = (const float*)d_in[4];
  const float* b2  = (const float*)d_in[5];
  float* out = (float*)d_out;
  char* wsb = (char*)d_ws;

  const size_t PROJ_B = (size_t)NREL * NN * 128 * 2;  // 38.4 MB bf16
  const size_t H_B    = (size_t)NN * 128 * 2;         // 12.8 MB
  auto need = [&](int R, int CAPR) {
    return PROJ_B + H_B + (size_t)R * NREL * NN * CAPR * 2 +
           (size_t)R * CS * 4 + 16 + (size_t)3 * MAXSPILL * 4 + CS * 4;
  };
  int R = (ws_size >= need(8, CAP8)) ? 8 : 1;
  int CAPR = (R == 8) ? CAP8 : CAP1;

  unsigned short* proj = (unsigned short*)wsb;
  unsigned short* h    = (unsigned short*)(wsb + PROJ_B);
  unsigned short* ell8 = (unsigned short*)(wsb + PROJ_B + H_B);
  size_t ellB = (size_t)R * NREL * NN * CAPR * 2;
  int* cnt8   = (int*)(wsb + PROJ_B + H_B + ellB);
  int* nspill = cnt8 + (size_t)R * CS;
  int* spill  = nspill + 4;
  int* cnt    = spill + 3 * MAXSPILL;

  // zero replica counters + spill count (contiguous)
  hipMemsetAsync(cnt8, 0, (size_t)R * CS * 4 + 16, stream);

  const int agg1Blocks = (NN * 32 + 255) / 256;
  const int agg2Blocks = (NN * 16 + 255) / 256;

  if (R == 8) {
    fused_build_gemm1_kernel<8, CAP8, true><<<GEMM1_BLKS, 256, 0, stream>>>(
        edges, cnt8, ell8, nspill, spill, x, W1, proj);
  } else {
    fused_build_gemm1_kernel<1, CAP1, false><<<GEMM1_BLKS, 256, 0, stream>>>(
        edges, cnt8, ell8, nspill, spill, x, W1, proj);
  }
  reduce_counts_kernel<<<((int)CS + 255) / 256, 256, 0, stream>>>(cnt8, cnt, R);
  agg1_all_kernel<<<agg1Blocks, 256, 0, stream>>>(
      proj, ell8, cnt8, cnt, nspill, spill, b1, h, R, CAPR);
  gemm2_kernel<<<dim3(G1X, 1, NREL), 256, 0, stream>>>(h, W2, cnt, proj);
  agg2_all_kernel<<<agg2Blocks, 256, 0, stream>>>(
      proj, ell8, cnt8, cnt, nspill, spill, b2, out, R, CAPR);
}

// Round 9
// 391.261 us; speedup vs baseline: 1.0032x; 1.0032x over previous
//
#include <hip/hip_runtime.h>

constexpr int NN = 50000;
constexpr int NREL = 3;
constexpr int NE = 400000;
constexpr int CAP = 24;        // ELL capacity; Poisson(8) tail at 24 ~ 4e-9/node
constexpr int MAXSPILL = 4096;

constexpr int G1X = (NN + 63) / 64;           // 782 row-tiles
constexpr int GEMM1_BLKS = G1X * 2 * NREL;    // 4692 blocks; >= 4688 edge chunks
constexpr int LDA = 68;                       // BK=64 + 4 pad (build GEMM)
constexpr int LDH = 132;                      // K=128 + 4 pad (fused h tile)

// ---- bf16 <-> f32 bit helpers (finite inputs; RNE on store) ----
__device__ __forceinline__ float b2f(unsigned short u) {
  union { unsigned int i; float f; } v; v.i = (unsigned int)u << 16; return v.f;
}
__device__ __forceinline__ unsigned short f2b(float f) {
  union { float f; unsigned int i; } v; v.f = f;
  unsigned int r = v.i + 0x7fffu + ((v.i >> 16) & 1u);
  return (unsigned short)(r >> 16);
}

// ---- fused: 1 GEMM tile of proj1_r = x@W1_r (bf16 out) + 256 edges of ELL build ----
// (round-7 proven structure: device atomics issued after first staging barrier,
//  consumed at kernel end; BK=64 two-stage; 33.8 KB LDS -> 3 blocks/CU)
__global__ __launch_bounds__(256, 3) void fused_build_gemm1_kernel(
    const int* __restrict__ edges, int* __restrict__ cnt_out, int* __restrict__ cnt_in,
    unsigned short* __restrict__ ell, int* __restrict__ nspill, int* __restrict__ spill,
    const float* __restrict__ x, const float* __restrict__ W1, unsigned short* __restrict__ proj1) {
  __shared__ float As[64][LDA];
  __shared__ float Bs[64][64];
  int t = threadIdx.x;

  // --- edge slice ---
  int eg = blockIdx.x * 256 + t;
  bool have = (eg < NREL * NE);
  int er = 0, es = 0, ed = 0;
  if (have) {
    er = eg / NE;
    int e = eg - er * NE;
    const int* b = edges + (size_t)er * 2 * NE;
    es = b[e];
    ed = b[NE + e];
  }

  // --- GEMM tile mapping ---
  int g = blockIdx.x;
  int r = g / (G1X * 2);
  int rem = g - r * (G1X * 2);
  int row0 = (rem >> 1) * 64;
  int col0 = (rem & 1) * 64;
  const float* W = W1 + (size_t)r * 128 * 128;
  unsigned short* C = proj1 + (size_t)r * NN * 128;

  int tx4 = (t & 15) << 2;
  int ty4 = (t >> 4) << 2;
  float acc[4][4] = {};
  int pos = 0;
  for (int k0 = 0; k0 < 128; k0 += 64) {
    if (k0) __syncthreads();
#pragma unroll
    for (int i = 0; i < 4; ++i) {
      int idx = t + i * 256;
      int rr = idx >> 4;
      int c4 = (idx & 15) << 2;
      int grow = row0 + rr;
      float4 v = make_float4(0.f, 0.f, 0.f, 0.f);
      if (grow < NN) v = *(const float4*)(x + (size_t)grow * 128 + k0 + c4);
      *(float4*)(&As[rr][c4]) = v;
    }
#pragma unroll
    for (int i = 0; i < 4; ++i) {
      int idx = t + i * 256;
      int k = idx >> 4;
      int c4 = (idx & 15) << 2;
      *(float4*)(&Bs[k][c4]) = *(const float4*)(W + (size_t)(k0 + k) * 128 + col0 + c4);
    }
    __syncthreads();
    if (k0 == 0 && have) {
      atomicAdd(cnt_out + (size_t)er * NN + es, 1);
      pos = atomicAdd(cnt_in + (size_t)er * NN + ed, 1);   // return hidden under K-loop
    }
#pragma unroll 8
    for (int k = 0; k < 64; k += 4) {
      float4 b0 = *(const float4*)(&Bs[k + 0][tx4]);
      float4 b1 = *(const float4*)(&Bs[k + 1][tx4]);
      float4 b2 = *(const float4*)(&Bs[k + 2][tx4]);
      float4 b3 = *(const float4*)(&Bs[k + 3][tx4]);
#pragma unroll
      for (int m = 0; m < 4; ++m) {
        float4 a = *(const float4*)(&As[ty4 + m][k]);
        acc[m][0] += a.x * b0.x + a.y * b1.x + a.z * b2.x + a.w * b3.x;
        acc[m][1] += a.x * b0.y + a.y * b1.y + a.z * b2.y + a.w * b3.y;
        acc[m][2] += a.x * b0.z + a.y * b1.z + a.z * b2.z + a.w * b3.z;
        acc[m][3] += a.x * b0.w + a.y * b1.w + a.z * b2.w + a.w * b3.w;
      }
    }
  }
#pragma unroll
  for (int m = 0; m < 4; ++m) {
    int row = row0 + ty4 + m;
    if (row < NN) {
      ushort4 o;
      o.x = f2b(acc[m][0]); o.y = f2b(acc[m][1]);
      o.z = f2b(acc[m][2]); o.w = f2b(acc[m][3]);
      *(ushort4*)(C + (size_t)row * 128 + col0 + tx4) = o;
    }
  }

  if (have) {
    if (pos < CAP) {
      ell[((size_t)er * NN + ed) * CAP + pos] = (unsigned short)es;
    } else {
      int i = atomicAdd(nspill, 1);
      if (i < MAXSPILL) { spill[3 * i] = er; spill[3 * i + 1] = ed; spill[3 * i + 2] = es; }
    }
  }
}

// ---- fused layer-1 aggregate + layer-2 GEMM: h lives in LDS only ----
// Phase A: 8 half-waves aggregate 64 h-rows (bias+relu, fp32) into Hs.
// Phase B: 3 relation GEMMs (BK=64 two-stage W2 staging), output row scale
//          rsqrt(deg_out_r) applied in epilogue (commutes), bf16 proj2 out.
__global__ __launch_bounds__(256, 3) void agg1_gemm2_kernel(
    const unsigned short* __restrict__ proj1, const unsigned short* __restrict__ ell,
    const int* __restrict__ cnt_out, const int* __restrict__ cnt_in,
    const int* __restrict__ nspill, const int* __restrict__ spill,
    const float* __restrict__ b1, const float* __restrict__ W2,
    unsigned short* __restrict__ proj2) {
  __shared__ float Hs[64][LDH];   // 33.8 KB
  __shared__ float Bs[64][64];    // 16.4 KB
  int t = threadIdx.x;
  int row0 = blockIdx.x * 64;
  int hw = t >> 5;
  int lane = t & 31;
  int f = lane * 4;
  int ns = min(*nspill, MAXSPILL);

  // ---- Phase A: aggregate h rows into LDS ----
  for (int sub = hw; sub < 64; sub += 8) {
    int row = row0 + sub;
    float4 hacc = make_float4(0.f, 0.f, 0.f, 0.f);
    if (row < NN) {
      float4 q0 = *(const float4*)(b1 + f);
      float4 q1 = *(const float4*)(b1 + 128 + f);
      float4 q2 = *(const float4*)(b1 + 256 + f);
      hacc = make_float4(q0.x + q1.x + q2.x, q0.y + q1.y + q2.y,
                         q0.z + q1.z + q2.z, q0.w + q1.w + q2.w);
      for (int r = 0; r < NREL; ++r) {
        const unsigned short* P = proj1 + (size_t)r * NN * 128;
        const int* co = cnt_out + (size_t)r * NN;
        int deg = cnt_in[(size_t)r * NN + row];
        int n = min(deg, CAP);
        const unsigned short* er = ell + ((size_t)r * NN + row) * CAP;
        float4 a0 = make_float4(0.f, 0.f, 0.f, 0.f);
        float4 a1 = make_float4(0.f, 0.f, 0.f, 0.f);
        int e = 0;
        for (; e + 1 < n; e += 2) {
          int s0 = er[e], s1 = er[e + 1];
          float w0 = rsqrtf((float)max(co[s0], 1));
          float w1 = rsqrtf((float)max(co[s1], 1));
          ushort4 u0 = *(const ushort4*)(P + (size_t)s0 * 128 + f);
          ushort4 u1 = *(const ushort4*)(P + (size_t)s1 * 128 + f);
          a0.x += w0 * b2f(u0.x); a0.y += w0 * b2f(u0.y);
          a0.z += w0 * b2f(u0.z); a0.w += w0 * b2f(u0.w);
          a1.x += w1 * b2f(u1.x); a1.y += w1 * b2f(u1.y);
          a1.z += w1 * b2f(u1.z); a1.w += w1 * b2f(u1.w);
        }
        if (e < n) {
          int s0 = er[e];
          float w0 = rsqrtf((float)max(co[s0], 1));
          ushort4 u0 = *(const ushort4*)(P + (size_t)s0 * 128 + f);
          a0.x += w0 * b2f(u0.x); a0.y += w0 * b2f(u0.y);
          a0.z += w0 * b2f(u0.z); a0.w += w0 * b2f(u0.w);
        }
        for (int i = 0; i < ns; ++i) {
          if (spill[3 * i] == r && spill[3 * i + 1] == row) {
            int s0 = spill[3 * i + 2];
            float w0 = rsqrtf((float)max(co[s0], 1));
            ushort4 u0 = *(const ushort4*)(P + (size_t)s0 * 128 + f);
            a0.x += w0 * b2f(u0.x); a0.y += w0 * b2f(u0.y);
            a0.z += w0 * b2f(u0.z); a0.w += w0 * b2f(u0.w);
          }
        }
        float si = rsqrtf((float)max(deg, 1));
        hacc.x += (a0.x + a1.x) * si; hacc.y += (a0.y + a1.y) * si;
        hacc.z += (a0.z + a1.z) * si; hacc.w += (a0.w + a1.w) * si;
      }
      hacc.x = fmaxf(hacc.x, 0.f); hacc.y = fmaxf(hacc.y, 0.f);
      hacc.z = fmaxf(hacc.z, 0.f); hacc.w = fmaxf(hacc.w, 0.f);
    }
    *(float4*)(&Hs[sub][f]) = hacc;
  }
  __syncthreads();

  // ---- Phase B: 3 relation GEMMs from LDS h tile ----
  int tx4 = (t & 15) << 2;
  int ty4 = (t >> 4) << 2;
  for (int r = 0; r < NREL; ++r) {
    const float* W = W2 + (size_t)r * 128 * 64;
    float acc[4][4] = {};
    for (int k0 = 0; k0 < 128; k0 += 64) {
      if (r || k0) __syncthreads();   // protect Bs overwrite
#pragma unroll
      for (int i = 0; i < 4; ++i) {
        int idx = t + i * 256;
        int k = idx >> 4;
        int c4 = (idx & 15) << 2;
        *(float4*)(&Bs[k][c4]) = *(const float4*)(W + (size_t)(k0 + k) * 64 + c4);
      }
      __syncthreads();
#pragma unroll 8
      for (int k = 0; k < 64; k += 4) {
        float4 w0 = *(const float4*)(&Bs[k + 0][tx4]);
        float4 w1 = *(const float4*)(&Bs[k + 1][tx4]);
        float4 w2 = *(const float4*)(&Bs[k + 2][tx4]);
        float4 w3 = *(const float4*)(&Bs[k + 3][tx4]);
#pragma unroll
        for (int m = 0; m < 4; ++m) {
          float4 a = *(const float4*)(&Hs[ty4 + m][k0 + k]);
          acc[m][0] += a.x * w0.x + a.y * w1.x + a.z * w2.x + a.w * w3.x;
          acc[m][1] += a.x * w0.y + a.y * w1.y + a.z * w2.y + a.w * w3.y;
          acc[m][2] += a.x * w0.z + a.y * w1.z + a.z * w2.z + a.w * w3.z;
          acc[m][3] += a.x * w0.w + a.y * w1.w + a.z * w2.w + a.w * w3.w;
        }
      }
    }
#pragma unroll
    for (int m = 0; m < 4; ++m) {
      int row = row0 + ty4 + m;
      if (row < NN) {
        float s = rsqrtf((float)max(cnt_out[(size_t)r * NN + row], 1));
        ushort4 o;
        o.x = f2b(acc[m][0] * s); o.y = f2b(acc[m][1] * s);
        o.z = f2b(acc[m][2] * s); o.w = f2b(acc[m][3] * s);
        *(ushort4*)(proj2 + (size_t)r * NN * 64 + (size_t)row * 64 + tx4) = o;
      }
    }
  }
}

// ---- layer-2 aggregate, all 3 relations, bias fused; quarter-wave per row ----
__global__ __launch_bounds__(256) void agg2_all_kernel(
    const unsigned short* __restrict__ proj2, const unsigned short* __restrict__ ell,
    const int* __restrict__ cnt_in,
    const int* __restrict__ nspill, const int* __restrict__ spill,
    const float* __restrict__ b2, float* __restrict__ out) {
  int row = (blockIdx.x * blockDim.x + threadIdx.x) >> 4;
  if (row >= NN) return;
  int lane = threadIdx.x & 15;
  int f = lane * 4;
  float4 q0 = *(const float4*)(b2 + f);
  float4 q1 = *(const float4*)(b2 + 64 + f);
  float4 q2 = *(const float4*)(b2 + 128 + f);
  float4 acc = make_float4(q0.x + q1.x + q2.x, q0.y + q1.y + q2.y,
                           q0.z + q1.z + q2.z, q0.w + q1.w + q2.w);
  int ns = min(*nspill, MAXSPILL);
  for (int r = 0; r < NREL; ++r) {
    const unsigned short* P = proj2 + (size_t)r * NN * 64;
    int deg = cnt_in[(size_t)r * NN + row];
    int n = min(deg, CAP);
    const unsigned short* er = ell + ((size_t)r * NN + row) * CAP;
    float4 a0 = make_float4(0.f, 0.f, 0.f, 0.f);
    float4 a1 = make_float4(0.f, 0.f, 0.f, 0.f);
    int e = 0;
    for (; e + 1 < n; e += 2) {
      int s0 = er[e], s1 = er[e + 1];
      ushort4 u0 = *(const ushort4*)(P + (size_t)s0 * 64 + f);
      ushort4 u1 = *(const ushort4*)(P + (size_t)s1 * 64 + f);
      a0.x += b2f(u0.x); a0.y += b2f(u0.y); a0.z += b2f(u0.z); a0.w += b2f(u0.w);
      a1.x += b2f(u1.x); a1.y += b2f(u1.y); a1.z += b2f(u1.z); a1.w += b2f(u1.w);
    }
    if (e < n) {
      int s0 = er[e];
      ushort4 u0 = *(const ushort4*)(P + (size_t)s0 * 64 + f);
      a0.x += b2f(u0.x); a0.y += b2f(u0.y); a0.z += b2f(u0.z); a0.w += b2f(u0.w);
    }
    for (int i = 0; i < ns; ++i) {
      if (spill[3 * i] == r && spill[3 * i + 1] == row) {
        int s0 = spill[3 * i + 2];
        ushort4 u0 = *(const ushort4*)(P + (size_t)s0 * 64 + f);
        a0.x += b2f(u0.x); a0.y += b2f(u0.y); a0.z += b2f(u0.z); a0.w += b2f(u0.w);
      }
    }
    float si = rsqrtf((float)max(deg, 1));
    acc.x += (a0.x + a1.x) * si; acc.y += (a0.y + a1.y) * si;
    acc.z += (a0.z + a1.z) * si; acc.w += (a0.w + a1.w) * si;
  }
  *(float4*)(out + (size_t)row * 64 + f) = acc;
}

extern "C" void kernel_launch(void* const* d_in, const int* in_sizes, int n_in,
                              void* d_out, int out_size, void* d_ws, size_t ws_size,
                              hipStream_t stream) {
  const float* x   = (const float*)d_in[0];
  const int* edges = (const int*)d_in[1];
  const float* W1  = (const float*)d_in[2];
  const float* b1  = (const float*)d_in[3];
  const float* W2  = (const float*)d_in[4];
  const float* b2  = (const float*)d_in[5];
  float* out = (float*)d_out;
  char* wsb = (char*)d_ws;

  // workspace layout (~66.2 MB; harness ws proven >= 111 MB in earlier rounds)
  const size_t PROJ1_B = (size_t)NREL * NN * 128 * 2;  // 38.4 MB bf16
  const size_t PROJ2_B = (size_t)NREL * NN * 64 * 2;   // 19.2 MB bf16 (separate: same-kernel RW)
  const size_t ELL_B   = (size_t)NREL * NN * CAP * 2;  // 7.2 MB
  unsigned short* proj1 = (unsigned short*)wsb;
  unsigned short* proj2 = (unsigned short*)(wsb + PROJ1_B);
  unsigned short* ell   = (unsigned short*)(wsb + PROJ1_B + PROJ2_B);
  int* cnt_out = (int*)(wsb + PROJ1_B + PROJ2_B + ELL_B);
  int* cnt_in  = cnt_out + (size_t)NREL * NN;
  int* nspill  = cnt_in + (size_t)NREL * NN;
  int* spill   = nspill + 4;

  // zero counters + spill count (contiguous)
  hipMemsetAsync(cnt_out, 0, (size_t)2 * NREL * NN * 4 + 16, stream);

  fused_build_gemm1_kernel<<<GEMM1_BLKS, 256, 0, stream>>>(
      edges, cnt_out, cnt_in, ell, nspill, spill, x, W1, proj1);
  agg1_gemm2_kernel<<<G1X, 256, 0, stream>>>(
      proj1, ell, cnt_out, cnt_in, nspill, spill, b1, W2, proj2);
  agg2_all_kernel<<<(NN * 16 + 255) / 256, 256, 0, stream>>>(
      proj2, ell, cnt_in, nspill, spill, b2, out);
}

// Round 10
// 296.280 us; speedup vs baseline: 1.3248x; 1.3206x over previous
//
#include <hip/hip_runtime.h>

constexpr int NN = 50000;
constexpr int NREL = 3;
constexpr int NE = 400000;
constexpr int CAP = 24;        // ELL capacity; Poisson(8) tail at 24 ~ 4e-9/node
constexpr int MAXSPILL = 4096;

constexpr int G1X = (NN + 63) / 64;           // 782 row-tiles
constexpr int GEMM1_BLKS = G1X * 2 * NREL;    // 4692 blocks; >= 4688 edge chunks
constexpr int LDA = 68;                       // BK=64 + 4 pad

// ---- bf16 <-> f32 bit helpers (finite inputs; RNE on store) ----
__device__ __forceinline__ float b2f(unsigned short u) {
  union { unsigned int i; float f; } v; v.i = (unsigned int)u << 16; return v.f;
}
__device__ __forceinline__ unsigned short f2b(float f) {
  union { float f; unsigned int i; } v; v.f = f;
  unsigned int r = v.i + 0x7fffu + ((v.i >> 16) & 1u);
  return (unsigned short)(r >> 16);
}

// ---- fused: 1 GEMM tile of proj1_r = x@W1_r (bf16 out) + 256 edges of ELL build ----
// Round-7 proven: atomics issued after first staging barrier, consumed at kernel
// end (hidden under K-loop); BK=64 two-stage; 33.8 KB LDS -> 3 blocks/CU.
__global__ __launch_bounds__(256, 3) void fused_build_gemm1_kernel(
    const int* __restrict__ edges, int* __restrict__ cnt_out, int* __restrict__ cnt_in,
    unsigned short* __restrict__ ell, int* __restrict__ nspill, int* __restrict__ spill,
    const float* __restrict__ x, const float* __restrict__ W1, unsigned short* __restrict__ proj1) {
  __shared__ float As[64][LDA];
  __shared__ float Bs[64][64];
  int t = threadIdx.x;

  int eg = blockIdx.x * 256 + t;
  bool have = (eg < NREL * NE);
  int er = 0, es = 0, ed = 0;
  if (have) {
    er = eg / NE;
    int e = eg - er * NE;
    const int* b = edges + (size_t)er * 2 * NE;
    es = b[e];
    ed = b[NE + e];
  }

  int g = blockIdx.x;
  int r = g / (G1X * 2);
  int rem = g - r * (G1X * 2);
  int row0 = (rem >> 1) * 64;
  int col0 = (rem & 1) * 64;
  const float* W = W1 + (size_t)r * 128 * 128;
  unsigned short* C = proj1 + (size_t)r * NN * 128;

  int tx4 = (t & 15) << 2;
  int ty4 = (t >> 4) << 2;
  float acc[4][4] = {};
  int pos = 0;
  for (int k0 = 0; k0 < 128; k0 += 64) {
    if (k0) __syncthreads();
#pragma unroll
    for (int i = 0; i < 4; ++i) {
      int idx = t + i * 256;
      int rr = idx >> 4;
      int c4 = (idx & 15) << 2;
      int grow = row0 + rr;
      float4 v = make_float4(0.f, 0.f, 0.f, 0.f);
      if (grow < NN) v = *(const float4*)(x + (size_t)grow * 128 + k0 + c4);
      *(float4*)(&As[rr][c4]) = v;
    }
#pragma unroll
    for (int i = 0; i < 4; ++i) {
      int idx = t + i * 256;
      int k = idx >> 4;
      int c4 = (idx & 15) << 2;
      *(float4*)(&Bs[k][c4]) = *(const float4*)(W + (size_t)(k0 + k) * 128 + col0 + c4);
    }
    __syncthreads();
    if (k0 == 0 && have) {
      atomicAdd(cnt_out + (size_t)er * NN + es, 1);
      pos = atomicAdd(cnt_in + (size_t)er * NN + ed, 1);
    }
#pragma unroll 8
    for (int k = 0; k < 64; k += 4) {
      float4 b0 = *(const float4*)(&Bs[k + 0][tx4]);
      float4 b1 = *(const float4*)(&Bs[k + 1][tx4]);
      float4 b2 = *(const float4*)(&Bs[k + 2][tx4]);
      float4 b3 = *(const float4*)(&Bs[k + 3][tx4]);
#pragma unroll
      for (int m = 0; m < 4; ++m) {
        float4 a = *(const float4*)(&As[ty4 + m][k]);
        acc[m][0] += a.x * b0.x + a.y * b1.x + a.z * b2.x + a.w * b3.x;
        acc[m][1] += a.x * b0.y + a.y * b1.y + a.z * b2.y + a.w * b3.y;
        acc[m][2] += a.x * b0.z + a.y * b1.z + a.z * b2.z + a.w * b3.z;
        acc[m][3] += a.x * b0.w + a.y * b1.w + a.z * b2.w + a.w * b3.w;
      }
    }
  }
#pragma unroll
  for (int m = 0; m < 4; ++m) {
    int row = row0 + ty4 + m;
    if (row < NN) {
      ushort4 o;
      o.x = f2b(acc[m][0]); o.y = f2b(acc[m][1]);
      o.z = f2b(acc[m][2]); o.w = f2b(acc[m][3]);
      *(ushort4*)(C + (size_t)row * 128 + col0 + tx4) = o;
    }
  }

  if (have) {
    if (pos < CAP) {
      ell[((size_t)er * NN + ed) * CAP + pos] = (unsigned short)es;
    } else {
      int i = atomicAdd(nspill, 1);
      if (i < MAXSPILL) { spill[3 * i] = er; spill[3 * i + 1] = ed; spill[3 * i + 2] = es; }
    }
  }
}

__global__ __launch_bounds__(256, 3) void gemm2_kernel(
    const unsigned short* __restrict__ h, const float* __restrict__ W2,
    const int* __restrict__ cnt_out, unsigned short* __restrict__ proj2) {
  __shared__ float As[64][LDA];
  __shared__ float Bs[64][64];
  int rel = blockIdx.z;
  const float* W = W2 + (size_t)rel * 128 * 64;
  const int* cs = cnt_out + (size_t)rel * NN;
  unsigned short* C = proj2 + (size_t)rel * NN * 64;
  int t = threadIdx.x;
  int row0 = blockIdx.x * 64;
  int tx4 = (t & 15) << 2;
  int ty4 = (t >> 4) << 2;
  float acc[4][4] = {};
  for (int k0 = 0; k0 < 128; k0 += 64) {
    if (k0) __syncthreads();
#pragma unroll
    for (int i = 0; i < 4; ++i) {
      int idx = t + i * 256;
      int r = idx >> 4;
      int c4 = (idx & 15) << 2;
      int grow = row0 + r;
      float4 v = make_float4(0.f, 0.f, 0.f, 0.f);
      if (grow < NN) {
        ushort4 u = *(const ushort4*)(h + (size_t)grow * 128 + k0 + c4);
        float s = rsqrtf((float)max(cs[grow], 1));
        v = make_float4(s * b2f(u.x), s * b2f(u.y), s * b2f(u.z), s * b2f(u.w));
      }
      *(float4*)(&As[r][c4]) = v;
    }
#pragma unroll
    for (int i = 0; i < 4; ++i) {
      int idx = t + i * 256;
      int k = idx >> 4;
      int c4 = (idx & 15) << 2;
      *(float4*)(&Bs[k][c4]) = *(const float4*)(W + (size_t)(k0 + k) * 64 + c4);
    }
    __syncthreads();
#pragma unroll 8
    for (int k = 0; k < 64; k += 4) {
      float4 b0 = *(const float4*)(&Bs[k + 0][tx4]);
      float4 b1 = *(const float4*)(&Bs[k + 1][tx4]);
      float4 b2 = *(const float4*)(&Bs[k + 2][tx4]);
      float4 b3 = *(const float4*)(&Bs[k + 3][tx4]);
#pragma unroll
      for (int m = 0; m < 4; ++m) {
        float4 a = *(const float4*)(&As[ty4 + m][k]);
        acc[m][0] += a.x * b0.x + a.y * b1.x + a.z * b2.x + a.w * b3.x;
        acc[m][1] += a.x * b0.y + a.y * b1.y + a.z * b2.y + a.w * b3.y;
        acc[m][2] += a.x * b0.z + a.y * b1.z + a.z * b2.z + a.w * b3.z;
        acc[m][3] += a.x * b0.w + a.y * b1.w + a.z * b2.w + a.w * b3.w;
      }
    }
  }
#pragma unroll
  for (int m = 0; m < 4; ++m) {
    int row = row0 + ty4 + m;
    if (row < NN) {
      ushort4 o;
      o.x = f2b(acc[m][0]); o.y = f2b(acc[m][1]);
      o.z = f2b(acc[m][2]); o.w = f2b(acc[m][3]);
      *(ushort4*)(C + (size_t)row * 64 + tx4) = o;
    }
  }
}

// ---- layer-1 aggregate, all 3 relations; 4-edge unroll for MLP; half-wave/row ----
__global__ __launch_bounds__(256) void agg1_all_kernel(
    const unsigned short* __restrict__ proj1, const unsigned short* __restrict__ ell,
    const int* __restrict__ cnt_in, const int* __restrict__ cnt_out,
    const int* __restrict__ nspill, const int* __restrict__ spill,
    const float* __restrict__ b1, unsigned short* __restrict__ h) {
  int row = (blockIdx.x * blockDim.x + threadIdx.x) >> 5;
  if (row >= NN) return;
  int lane = threadIdx.x & 31;
  int f = lane * 4;
  float4 q0 = *(const float4*)(b1 + f);
  float4 q1 = *(const float4*)(b1 + 128 + f);
  float4 q2 = *(const float4*)(b1 + 256 + f);
  float4 acc = make_float4(q0.x + q1.x + q2.x, q0.y + q1.y + q2.y,
                           q0.z + q1.z + q2.z, q0.w + q1.w + q2.w);
  int ns = min(*nspill, MAXSPILL);
  for (int r = 0; r < NREL; ++r) {
    const unsigned short* P = proj1 + (size_t)r * NN * 128;
    const int* co = cnt_out + (size_t)r * NN;
    int deg = cnt_in[(size_t)r * NN + row];
    int n = min(deg, CAP);
    const unsigned short* er = ell + ((size_t)r * NN + row) * CAP;
    float4 a0 = make_float4(0.f, 0.f, 0.f, 0.f);
    float4 a1 = make_float4(0.f, 0.f, 0.f, 0.f);
    float4 a2 = make_float4(0.f, 0.f, 0.f, 0.f);
    float4 a3 = make_float4(0.f, 0.f, 0.f, 0.f);
    int e = 0;
    for (; e + 3 < n; e += 4) {
      int s0 = er[e], s1 = er[e + 1], s2 = er[e + 2], s3 = er[e + 3];
      float w0 = rsqrtf((float)max(co[s0], 1));
      float w1 = rsqrtf((float)max(co[s1], 1));
      float w2 = rsqrtf((float)max(co[s2], 1));
      float w3 = rsqrtf((float)max(co[s3], 1));
      ushort4 u0 = *(const ushort4*)(P + (size_t)s0 * 128 + f);
      ushort4 u1 = *(const ushort4*)(P + (size_t)s1 * 128 + f);
      ushort4 u2 = *(const ushort4*)(P + (size_t)s2 * 128 + f);
      ushort4 u3 = *(const ushort4*)(P + (size_t)s3 * 128 + f);
      a0.x += w0 * b2f(u0.x); a0.y += w0 * b2f(u0.y); a0.z += w0 * b2f(u0.z); a0.w += w0 * b2f(u0.w);
      a1.x += w1 * b2f(u1.x); a1.y += w1 * b2f(u1.y); a1.z += w1 * b2f(u1.z); a1.w += w1 * b2f(u1.w);
      a2.x += w2 * b2f(u2.x); a2.y += w2 * b2f(u2.y); a2.z += w2 * b2f(u2.z); a2.w += w2 * b2f(u2.w);
      a3.x += w3 * b2f(u3.x); a3.y += w3 * b2f(u3.y); a3.z += w3 * b2f(u3.z); a3.w += w3 * b2f(u3.w);
    }
    for (; e < n; ++e) {
      int s0 = er[e];
      float w0 = rsqrtf((float)max(co[s0], 1));
      ushort4 u0 = *(const ushort4*)(P + (size_t)s0 * 128 + f);
      a0.x += w0 * b2f(u0.x); a0.y += w0 * b2f(u0.y); a0.z += w0 * b2f(u0.z); a0.w += w0 * b2f(u0.w);
    }
    for (int i = 0; i < ns; ++i) {
      if (spill[3 * i] == r && spill[3 * i + 1] == row) {
        int s0 = spill[3 * i + 2];
        float w0 = rsqrtf((float)max(co[s0], 1));
        ushort4 u0 = *(const ushort4*)(P + (size_t)s0 * 128 + f);
        a0.x += w0 * b2f(u0.x); a0.y += w0 * b2f(u0.y); a0.z += w0 * b2f(u0.z); a0.w += w0 * b2f(u0.w);
      }
    }
    float si = rsqrtf((float)max(deg, 1));
    acc.x += (a0.x + a1.x + a2.x + a3.x) * si;
    acc.y += (a0.y + a1.y + a2.y + a3.y) * si;
    acc.z += (a0.z + a1.z + a2.z + a3.z) * si;
    acc.w += (a0.w + a1.w + a2.w + a3.w) * si;
  }
  ushort4 o;
  o.x = f2b(fmaxf(acc.x, 0.f)); o.y = f2b(fmaxf(acc.y, 0.f));
  o.z = f2b(fmaxf(acc.z, 0.f)); o.w = f2b(fmaxf(acc.w, 0.f));
  *(ushort4*)(h + (size_t)row * 128 + f) = o;
}

// ---- layer-2 aggregate, all 3 relations; 4-edge unroll; quarter-wave/row ----
__global__ __launch_bounds__(256) void agg2_all_kernel(
    const unsigned short* __restrict__ proj2, const unsigned short* __restrict__ ell,
    const int* __restrict__ cnt_in,
    const int* __restrict__ nspill, const int* __restrict__ spill,
    const float* __restrict__ b2, float* __restrict__ out) {
  int row = (blockIdx.x * blockDim.x + threadIdx.x) >> 4;
  if (row >= NN) return;
  int lane = threadIdx.x & 15;
  int f = lane * 4;
  float4 q0 = *(const float4*)(b2 + f);
  float4 q1 = *(const float4*)(b2 + 64 + f);
  float4 q2 = *(const float4*)(b2 + 128 + f);
  float4 acc = make_float4(q0.x + q1.x + q2.x, q0.y + q1.y + q2.y,
                           q0.z + q1.z + q2.z, q0.w + q1.w + q2.w);
  int ns = min(*nspill, MAXSPILL);
  for (int r = 0; r < NREL; ++r) {
    const unsigned short* P = proj2 + (size_t)r * NN * 64;
    int deg = cnt_in[(size_t)r * NN + row];
    int n = min(deg, CAP);
    const unsigned short* er = ell + ((size_t)r * NN + row) * CAP;
    float4 a0 = make_float4(0.f, 0.f, 0.f, 0.f);
    float4 a1 = make_float4(0.f, 0.f, 0.f, 0.f);
    float4 a2 = make_float4(0.f, 0.f, 0.f, 0.f);
    float4 a3 = make_float4(0.f, 0.f, 0.f, 0.f);
    int e = 0;
    for (; e + 3 < n; e += 4) {
      int s0 = er[e], s1 = er[e + 1], s2 = er[e + 2], s3 = er[e + 3];
      ushort4 u0 = *(const ushort4*)(P + (size_t)s0 * 64 + f);
      ushort4 u1 = *(const ushort4*)(P + (size_t)s1 * 64 + f);
      ushort4 u2 = *(const ushort4*)(P + (size_t)s2 * 64 + f);
      ushort4 u3 = *(const ushort4*)(P + (size_t)s3 * 64 + f);
      a0.x += b2f(u0.x); a0.y += b2f(u0.y); a0.z += b2f(u0.z); a0.w += b2f(u0.w);
      a1.x += b2f(u1.x); a1.y += b2f(u1.y); a1.z += b2f(u1.z); a1.w += b2f(u1.w);
      a2.x += b2f(u2.x); a2.y += b2f(u2.y); a2.z += b2f(u2.z); a2.w += b2f(u2.w);
      a3.x += b2f(u3.x); a3.y += b2f(u3.y); a3.z += b2f(u3.z); a3.w += b2f(u3.w);
    }
    for (; e < n; ++e) {
      int s0 = er[e];
      ushort4 u0 = *(const ushort4*)(P + (size_t)s0 * 64 + f);
      a0.x += b2f(u0.x); a0.y += b2f(u0.y); a0.z += b2f(u0.z); a0.w += b2f(u0.w);
    }
    for (int i = 0; i < ns; ++i) {
      if (spill[3 * i] == r && spill[3 * i + 1] == row) {
        int s0 = spill[3 * i + 2];
        ushort4 u0 = *(const ushort4*)(P + (size_t)s0 * 64 + f);
        a0.x += b2f(u0.x); a0.y += b2f(u0.y); a0.z += b2f(u0.z); a0.w += b2f(u0.w);
      }
    }
    float si = rsqrtf((float)max(deg, 1));
    acc.x += (a0.x + a1.x + a2.x + a3.x) * si;
    acc.y += (a0.y + a1.y + a2.y + a3.y) * si;
    acc.z += (a0.z + a1.z + a2.z + a3.z) * si;
    acc.w += (a0.w + a1.w + a2.w + a3.w) * si;
  }
  *(float4*)(out + (size_t)row * 64 + f) = acc;
}

extern "C" void kernel_launch(void* const* d_in, const int* in_sizes, int n_in,
                              void* d_out, int out_size, void* d_ws, size_t ws_size,
                              hipStream_t stream) {
  const float* x   = (const float*)d_in[0];
  const int* edges = (const int*)d_in[1];
  const float* W1  = (const float*)d_in[2];
  const float* b1  = (const float*)d_in[3];
  const float* W2  = (const float*)d_in[4];
  const float* b2  = (const float*)d_in[5];
  float* out = (float*)d_out;
  char* wsb = (char*)d_ws;

  // workspace layout (~66 MB)
  const size_t PROJ1_B = (size_t)NREL * NN * 128 * 2;  // 38.4 MB bf16
  const size_t H_B     = (size_t)NN * 128 * 2;         // 12.8 MB bf16
  const size_t PROJ2_B = (size_t)NREL * NN * 64 * 2;   // 19.2 MB bf16 (overlaps proj1 region reuse-safe? keep separate)
  const size_t ELL_B   = (size_t)NREL * NN * CAP * 2;  // 7.2 MB
  unsigned short* proj1 = (unsigned short*)wsb;
  unsigned short* h     = (unsigned short*)(wsb + PROJ1_B);
  unsigned short* ell   = (unsigned short*)(wsb + PROJ1_B + H_B);
  int* cnt_out = (int*)(wsb + PROJ1_B + H_B + ELL_B);
  int* cnt_in  = cnt_out + (size_t)NREL * NN;
  int* nspill  = cnt_in + (size_t)NREL * NN;
  int* spill   = nspill + 4;
  // proj2 reuses the proj1 region (proj1 dead after agg1)
  unsigned short* proj2 = proj1;
  (void)PROJ2_B;

  hipMemsetAsync(cnt_out, 0, (size_t)2 * NREL * NN * 4 + 16, stream);

  fused_build_gemm1_kernel<<<GEMM1_BLKS, 256, 0, stream>>>(
      edges, cnt_out, cnt_in, ell, nspill, spill, x, W1, proj1);
  agg1_all_kernel<<<(NN * 32 + 255) / 256, 256, 0, stream>>>(
      proj1, ell, cnt_in, cnt_out, nspill, spill, b1, h);
  gemm2_kernel<<<dim3(G1X, 1, NREL), 256, 0, stream>>>(h, W2, cnt_out, proj2);
  agg2_all_kernel<<<(NN * 16 + 255) / 256, 256, 0, stream>>>(
      proj2, ell, cnt_in, nspill, spill, b2, out);
}

// Round 11
// 269.913 us; speedup vs baseline: 1.4543x; 1.0977x over previous
//
#include <hip/hip_runtime.h>

constexpr int NN = 50000;
constexpr int NREL = 3;
constexpr int NE = 400000;
constexpr int CAP = 24;        // ELL capacity; Poisson(8) tail at 24 ~ 4e-9/node
constexpr int MAXSPILL = 4096;

constexpr int G1X = (NN + 63) / 64;           // 782 row-tiles
constexpr int GEMM1_BLKS = G1X * 2 * NREL;    // 4692 blocks; >= 4688 edge chunks
constexpr int LDA = 68;                       // BK=64 + 4 pad

// ---- bf16 <-> f32 bit helpers (finite inputs; RNE on store) ----
__device__ __forceinline__ float b2f(unsigned short u) {
  union { unsigned int i; float f; } v; v.i = (unsigned int)u << 16; return v.f;
}
__device__ __forceinline__ unsigned short f2b(float f) {
  union { float f; unsigned int i; } v; v.f = f;
  unsigned int r = v.i + 0x7fffu + ((v.i >> 16) & 1u);
  return (unsigned short)(r >> 16);
}

// ---- fused: 1 GEMM tile of proj1_r = x@W1_r (bf16 out) + 256 edges of ELL build ----
// Atomics issued after first staging barrier, consumed at kernel end (hidden
// under the K-loop); BK=64 two-stage; 33.8 KB LDS -> 3 blocks/CU.
__global__ __launch_bounds__(256, 3) void fused_build_gemm1_kernel(
    const int* __restrict__ edges, int* __restrict__ cnt_out, int* __restrict__ cnt_in,
    unsigned short* __restrict__ ell, int* __restrict__ nspill, int* __restrict__ spill,
    const float* __restrict__ x, const float* __restrict__ W1, unsigned short* __restrict__ proj1) {
  __shared__ float As[64][LDA];
  __shared__ float Bs[64][64];
  int t = threadIdx.x;

  int eg = blockIdx.x * 256 + t;
  bool have = (eg < NREL * NE);
  int er = 0, es = 0, ed = 0;
  if (have) {
    er = eg / NE;
    int e = eg - er * NE;
    const int* b = edges + (size_t)er * 2 * NE;
    es = b[e];
    ed = b[NE + e];
  }

  int g = blockIdx.x;
  int r = g / (G1X * 2);
  int rem = g - r * (G1X * 2);
  int row0 = (rem >> 1) * 64;
  int col0 = (rem & 1) * 64;
  const float* W = W1 + (size_t)r * 128 * 128;
  unsigned short* C = proj1 + (size_t)r * NN * 128;

  int tx4 = (t & 15) << 2;
  int ty4 = (t >> 4) << 2;
  float acc[4][4] = {};
  int pos = 0;
  for (int k0 = 0; k0 < 128; k0 += 64) {
    if (k0) __syncthreads();
#pragma unroll
    for (int i = 0; i < 4; ++i) {
      int idx = t + i * 256;
      int rr = idx >> 4;
      int c4 = (idx & 15) << 2;
      int grow = row0 + rr;
      float4 v = make_float4(0.f, 0.f, 0.f, 0.f);
      if (grow < NN) v = *(const float4*)(x + (size_t)grow * 128 + k0 + c4);
      *(float4*)(&As[rr][c4]) = v;
    }
#pragma unroll
    for (int i = 0; i < 4; ++i) {
      int idx = t + i * 256;
      int k = idx >> 4;
      int c4 = (idx & 15) << 2;
      *(float4*)(&Bs[k][c4]) = *(const float4*)(W + (size_t)(k0 + k) * 128 + col0 + c4);
    }
    __syncthreads();
    if (k0 == 0 && have) {
      atomicAdd(cnt_out + (size_t)er * NN + es, 1);
      pos = atomicAdd(cnt_in + (size_t)er * NN + ed, 1);
    }
#pragma unroll 8
    for (int k = 0; k < 64; k += 4) {
      float4 b0 = *(const float4*)(&Bs[k + 0][tx4]);
      float4 b1 = *(const float4*)(&Bs[k + 1][tx4]);
      float4 b2 = *(const float4*)(&Bs[k + 2][tx4]);
      float4 b3 = *(const float4*)(&Bs[k + 3][tx4]);
#pragma unroll
      for (int m = 0; m < 4; ++m) {
        float4 a = *(const float4*)(&As[ty4 + m][k]);
        acc[m][0] += a.x * b0.x + a.y * b1.x + a.z * b2.x + a.w * b3.x;
        acc[m][1] += a.x * b0.y + a.y * b1.y + a.z * b2.y + a.w * b3.y;
        acc[m][2] += a.x * b0.z + a.y * b1.z + a.z * b2.z + a.w * b3.z;
        acc[m][3] += a.x * b0.w + a.y * b1.w + a.z * b2.w + a.w * b3.w;
      }
    }
  }
#pragma unroll
  for (int m = 0; m < 4; ++m) {
    int row = row0 + ty4 + m;
    if (row < NN) {
      ushort4 o;
      o.x = f2b(acc[m][0]); o.y = f2b(acc[m][1]);
      o.z = f2b(acc[m][2]); o.w = f2b(acc[m][3]);
      *(ushort4*)(C + (size_t)row * 128 + col0 + tx4) = o;
    }
  }

  if (have) {
    if (pos < CAP) {
      ell[((size_t)er * NN + ed) * CAP + pos] = (unsigned short)es;
    } else {
      int i = atomicAdd(nspill, 1);
      if (i < MAXSPILL) { spill[3 * i] = er; spill[3 * i + 1] = ed; spill[3 * i + 2] = es; }
    }
  }
}

__global__ __launch_bounds__(256, 3) void gemm2_kernel(
    const unsigned short* __restrict__ h, const float* __restrict__ W2,
    const int* __restrict__ cnt_out, unsigned short* __restrict__ proj2) {
  __shared__ float As[64][LDA];
  __shared__ float Bs[64][64];
  int rel = blockIdx.z;
  const float* W = W2 + (size_t)rel * 128 * 64;
  const int* cs = cnt_out + (size_t)rel * NN;
  unsigned short* C = proj2 + (size_t)rel * NN * 64;
  int t = threadIdx.x;
  int row0 = blockIdx.x * 64;
  int tx4 = (t & 15) << 2;
  int ty4 = (t >> 4) << 2;
  float acc[4][4] = {};
  for (int k0 = 0; k0 < 128; k0 += 64) {
    if (k0) __syncthreads();
#pragma unroll
    for (int i = 0; i < 4; ++i) {
      int idx = t + i * 256;
      int r = idx >> 4;
      int c4 = (idx & 15) << 2;
      int grow = row0 + r;
      float4 v = make_float4(0.f, 0.f, 0.f, 0.f);
      if (grow < NN) {
        ushort4 u = *(const ushort4*)(h + (size_t)grow * 128 + k0 + c4);
        float s = rsqrtf((float)max(cs[grow], 1));
        v = make_float4(s * b2f(u.x), s * b2f(u.y), s * b2f(u.z), s * b2f(u.w));
      }
      *(float4*)(&As[r][c4]) = v;
    }
#pragma unroll
    for (int i = 0; i < 4; ++i) {
      int idx = t + i * 256;
      int k = idx >> 4;
      int c4 = (idx & 15) << 2;
      *(float4*)(&Bs[k][c4]) = *(const float4*)(W + (size_t)(k0 + k) * 64 + c4);
    }
    __syncthreads();
#pragma unroll 8
    for (int k = 0; k < 64; k += 4) {
      float4 b0 = *(const float4*)(&Bs[k + 0][tx4]);
      float4 b1 = *(const float4*)(&Bs[k + 1][tx4]);
      float4 b2 = *(const float4*)(&Bs[k + 2][tx4]);
      float4 b3 = *(const float4*)(&Bs[k + 3][tx4]);
#pragma unroll
      for (int m = 0; m < 4; ++m) {
        float4 a = *(const float4*)(&As[ty4 + m][k]);
        acc[m][0] += a.x * b0.x + a.y * b1.x + a.z * b2.x + a.w * b3.x;
        acc[m][1] += a.x * b0.y + a.y * b1.y + a.z * b2.y + a.w * b3.y;
        acc[m][2] += a.x * b0.z + a.y * b1.z + a.z * b2.z + a.w * b3.z;
        acc[m][3] += a.x * b0.w + a.y * b1.w + a.z * b2.w + a.w * b3.w;
      }
    }
  }
#pragma unroll
  for (int m = 0; m < 4; ++m) {
    int row = row0 + ty4 + m;
    if (row < NN) {
      ushort4 o;
      o.x = f2b(acc[m][0]); o.y = f2b(acc[m][1]);
      o.z = f2b(acc[m][2]); o.w = f2b(acc[m][3]);
      *(ushort4*)(C + (size_t)row * 64 + tx4) = o;
    }
  }
}

// ---- layer-1 aggregate, all 3 relations, bias+relu fused; 2-edge unroll (proven
// optimum: deeper unroll costs occupancy, TLP > ILP here); half-wave per row ----
__global__ __launch_bounds__(256) void agg1_all_kernel(
    const unsigned short* __restrict__ proj1, const unsigned short* __restrict__ ell,
    const int* __restrict__ cnt_in, const int* __restrict__ cnt_out,
    const int* __restrict__ nspill, const int* __restrict__ spill,
    const float* __restrict__ b1, unsigned short* __restrict__ h) {
  int row = (blockIdx.x * blockDim.x + threadIdx.x) >> 5;
  if (row >= NN) return;
  int lane = threadIdx.x & 31;
  int f = lane * 4;
  float4 q0 = *(const float4*)(b1 + f);
  float4 q1 = *(const float4*)(b1 + 128 + f);
  float4 q2 = *(const float4*)(b1 + 256 + f);
  float4 acc = make_float4(q0.x + q1.x + q2.x, q0.y + q1.y + q2.y,
                           q0.z + q1.z + q2.z, q0.w + q1.w + q2.w);
  int ns = min(*nspill, MAXSPILL);
  for (int r = 0; r < NREL; ++r) {
    const unsigned short* P = proj1 + (size_t)r * NN * 128;
    const int* co = cnt_out + (size_t)r * NN;
    int deg = cnt_in[(size_t)r * NN + row];
    int n = min(deg, CAP);
    const unsigned short* er = ell + ((size_t)r * NN + row) * CAP;
    float4 a0 = make_float4(0.f, 0.f, 0.f, 0.f);
    float4 a1 = make_float4(0.f, 0.f, 0.f, 0.f);
    int e = 0;
    for (; e + 1 < n; e += 2) {
      int s0 = er[e], s1 = er[e + 1];
      float w0 = rsqrtf((float)max(co[s0], 1));
      float w1 = rsqrtf((float)max(co[s1], 1));
      ushort4 u0 = *(const ushort4*)(P + (size_t)s0 * 128 + f);
      ushort4 u1 = *(const ushort4*)(P + (size_t)s1 * 128 + f);
      a0.x += w0 * b2f(u0.x); a0.y += w0 * b2f(u0.y);
      a0.z += w0 * b2f(u0.z); a0.w += w0 * b2f(u0.w);
      a1.x += w1 * b2f(u1.x); a1.y += w1 * b2f(u1.y);
      a1.z += w1 * b2f(u1.z); a1.w += w1 * b2f(u1.w);
    }
    if (e < n) {
      int s0 = er[e];
      float w0 = rsqrtf((float)max(co[s0], 1));
      ushort4 u0 = *(const ushort4*)(P + (size_t)s0 * 128 + f);
      a0.x += w0 * b2f(u0.x); a0.y += w0 * b2f(u0.y);
      a0.z += w0 * b2f(u0.z); a0.w += w0 * b2f(u0.w);
    }
    for (int i = 0; i < ns; ++i) {
      if (spill[3 * i] == r && spill[3 * i + 1] == row) {
        int s0 = spill[3 * i + 2];
        float w0 = rsqrtf((float)max(co[s0], 1));
        ushort4 u0 = *(const ushort4*)(P + (size_t)s0 * 128 + f);
        a0.x += w0 * b2f(u0.x); a0.y += w0 * b2f(u0.y);
        a0.z += w0 * b2f(u0.z); a0.w += w0 * b2f(u0.w);
      }
    }
    float si = rsqrtf((float)max(deg, 1));
    acc.x += (a0.x + a1.x) * si; acc.y += (a0.y + a1.y) * si;
    acc.z += (a0.z + a1.z) * si; acc.w += (a0.w + a1.w) * si;
  }
  ushort4 o;
  o.x = f2b(fmaxf(acc.x, 0.f)); o.y = f2b(fmaxf(acc.y, 0.f));
  o.z = f2b(fmaxf(acc.z, 0.f)); o.w = f2b(fmaxf(acc.w, 0.f));
  *(ushort4*)(h + (size_t)row * 128 + f) = o;
}

// ---- layer-2 aggregate, all 3 relations, bias fused; 2-edge unroll; quarter-wave/row ----
__global__ __launch_bounds__(256) void agg2_all_kernel(
    const unsigned short* __restrict__ proj2, const unsigned short* __restrict__ ell,
    const int* __restrict__ cnt_in,
    const int* __restrict__ nspill, const int* __restrict__ spill,
    const float* __restrict__ b2, float* __restrict__ out) {
  int row = (blockIdx.x * blockDim.x + threadIdx.x) >> 4;
  if (row >= NN) return;
  int lane = threadIdx.x & 15;
  int f = lane * 4;
  float4 q0 = *(const float4*)(b2 + f);
  float4 q1 = *(const float4*)(b2 + 64 + f);
  float4 q2 = *(const float4*)(b2 + 128 + f);
  float4 acc = make_float4(q0.x + q1.x + q2.x, q0.y + q1.y + q2.y,
                           q0.z + q1.z + q2.z, q0.w + q1.w + q2.w);
  int ns = min(*nspill, MAXSPILL);
  for (int r = 0; r < NREL; ++r) {
    const unsigned short* P = proj2 + (size_t)r * NN * 64;
    int deg = cnt_in[(size_t)r * NN + row];
    int n = min(deg, CAP);
    const unsigned short* er = ell + ((size_t)r * NN + row) * CAP;
    float4 a0 = make_float4(0.f, 0.f, 0.f, 0.f);
    float4 a1 = make_float4(0.f, 0.f, 0.f, 0.f);
    int e = 0;
    for (; e + 1 < n; e += 2) {
      int s0 = er[e], s1 = er[e + 1];
      ushort4 u0 = *(const ushort4*)(P + (size_t)s0 * 64 + f);
      ushort4 u1 = *(const ushort4*)(P + (size_t)s1 * 64 + f);
      a0.x += b2f(u0.x); a0.y += b2f(u0.y); a0.z += b2f(u0.z); a0.w += b2f(u0.w);
      a1.x += b2f(u1.x); a1.y += b2f(u1.y); a1.z += b2f(u1.z); a1.w += b2f(u1.w);
    }
    if (e < n) {
      int s0 = er[e];
      ushort4 u0 = *(const ushort4*)(P + (size_t)s0 * 64 + f);
      a0.x += b2f(u0.x); a0.y += b2f(u0.y); a0.z += b2f(u0.z); a0.w += b2f(u0.w);
    }
    for (int i = 0; i < ns; ++i) {
      if (spill[3 * i] == r && spill[3 * i + 1] == row) {
        int s0 = spill[3 * i + 2];
        ushort4 u0 = *(const ushort4*)(P + (size_t)s0 * 64 + f);
        a0.x += b2f(u0.x); a0.y += b2f(u0.y); a0.z += b2f(u0.z); a0.w += b2f(u0.w);
      }
    }
    float si = rsqrtf((float)max(deg, 1));
    acc.x += (a0.x + a1.x) * si; acc.y += (a0.y + a1.y) * si;
    acc.z += (a0.z + a1.z) * si; acc.w += (a0.w + a1.w) * si;
  }
  *(float4*)(out + (size_t)row * 64 + f) = acc;
}

extern "C" void kernel_launch(void* const* d_in, const int* in_sizes, int n_in,
                              void* d_out, int out_size, void* d_ws, size_t ws_size,
                              hipStream_t stream) {
  const float* x   = (const float*)d_in[0];
  const int* edges = (const int*)d_in[1];
  const float* W1  = (const float*)d_in[2];
  const float* b1  = (const float*)d_in[3];
  const float* W2  = (const float*)d_in[4];
  const float* b2  = (const float*)d_in[5];
  float* out = (float*)d_out;
  char* wsb = (char*)d_ws;

  // workspace layout (~59 MB)
  const size_t PROJ1_B = (size_t)NREL * NN * 128 * 2;  // 38.4 MB bf16
  const size_t H_B     = (size_t)NN * 128 * 2;         // 12.8 MB bf16
  const size_t ELL_B   = (size_t)NREL * NN * CAP * 2;  // 7.2 MB
  unsigned short* proj1 = (unsigned short*)wsb;
  unsigned short* h     = (unsigned short*)(wsb + PROJ1_B);
  unsigned short* ell   = (unsigned short*)(wsb + PROJ1_B + H_B);
  int* cnt_out = (int*)(wsb + PROJ1_B + H_B + ELL_B);
  int* cnt_in  = cnt_out + (size_t)NREL * NN;
  int* nspill  = cnt_in + (size_t)NREL * NN;
  int* spill   = nspill + 4;
  unsigned short* proj2 = proj1;   // proj1 dead after agg1; reuse region

  hipMemsetAsync(cnt_out, 0, (size_t)2 * NREL * NN * 4 + 16, stream);

  fused_build_gemm1_kernel<<<GEMM1_BLKS, 256, 0, stream>>>(
      edges, cnt_out, cnt_in, ell, nspill, spill, x, W1, proj1);
  agg1_all_kernel<<<(NN * 32 + 255) / 256, 256, 0, stream>>>(
      proj1, ell, cnt_in, cnt_out, nspill, spill, b1, h);
  gemm2_kernel<<<dim3(G1X, 1, NREL), 256, 0, stream>>>(h, W2, cnt_out, proj2);
  agg2_all_kernel<<<(NN * 16 + 255) / 256, 256, 0, stream>>>(
      proj2, ell, cnt_in, nspill, spill, b2, out);
}